// Round 2
// baseline (597.421 us; speedup 1.0000x reference)
//
#include <hip/hip_runtime.h>
#include <math.h>

#define N_OPS 320
#define ROWS 32          // rows per chunk (2 chunks per block)
#define TP_ROW 238       // 34*7 floats
#define FAN_ROW 80
#define RED_ROW 34

__global__ __launch_bounds__(256) void mahjong_kernel(
    const float* __restrict__ meta,        // (N,6)
    const float* __restrict__ wall,        // (N,34,5)
    const float* __restrict__ tile_prep,   // (N,320,34,7)
    const float* __restrict__ fan_prep,    // (N,320,80)
    const float* __restrict__ redundant,   // (N,320,34)
    const float* __restrict__ W_throw,     // (11)
    const float* __restrict__ b_throw,     // (1)
    const float* __restrict__ fan_coeff,   // (80)
    const float* __restrict__ fan_mult,    // (80)
    const float* __restrict__ tile_coeff,  // (34)
    float* __restrict__ out_max,           // (N,5)
    float* __restrict__ out_weighted,      // (N,34)
    int n)
{
    const int blk  = blockIdx.x;
    const int b    = blk / 5;
    const int g    = blk % 5;
    const int tid  = threadIdx.x;
    const int wave = tid >> 6;
    const int lane = tid & 63;

    __shared__ __align__(16) float tp_sm[ROWS * TP_ROW];    // 7616 floats
    __shared__ __align__(16) float fan_sm[ROWS * FAN_ROW];  // 2560
    __shared__ __align__(16) float red_sm[ROWS * RED_ROW];  // 1088
    __shared__ float prob_sm[34];
    __shared__ float fc_sm[80];
    __shared__ float pprod[8][32];
    __shared__ float psum[8][32];
    __shared__ float final_sm[ROWS];
    __shared__ float acc_sm[4][34];

    // ---- stage 0: prob_throw (Linear(11,1)) and fused fan coeff ----
    if (tid < 34) {
        float acc = b_throw[0];
        #pragma unroll
        for (int j = 0; j < 6; ++j) acc += meta[(size_t)b * 6 + j] * W_throw[j];
        const float* w = wall + ((size_t)b * 34 + tid) * 5;
        #pragma unroll
        for (int j = 0; j < 5; ++j) acc += w[j] * W_throw[6 + j];
        prob_sm[tid] = acc;
    }
    if (tid >= 64 && tid < 144) {
        int f = tid - 64;
        fc_sm[f] = fan_coeff[f] * fan_mult[f];
    }

    const int s = tid >> 5;   // 0..7  work-slice within a row
    const int r = tid & 31;   // row within chunk

    float acc3 = 0.0f;        // stage-3 accumulator (per wave, lane<34)
    float fsum_part = 0.0f;   // g==0: per-thread (tid<32) running sum of finals

    for (int c = 0; c < 2; ++c) {
        const size_t row0 = (size_t)b * N_OPS + g * 64 + c * ROWS;

        __syncthreads();  // protect LDS slabs from previous chunk's readers

        // ---- cooperative coalesced slab loads into LDS ----
        {
            const float2* src = (const float2*)(tile_prep + row0 * TP_ROW);
            float2* dst = (float2*)tp_sm;
            #pragma unroll
            for (int i = tid; i < ROWS * TP_ROW / 2; i += 256) dst[i] = src[i];
        }
        {
            const float4* src = (const float4*)(fan_prep + row0 * FAN_ROW);
            float4* dst = (float4*)fan_sm;
            #pragma unroll
            for (int i = tid; i < ROWS * FAN_ROW / 4; i += 256) dst[i] = src[i];
        }
        {
            const float2* src = (const float2*)(redundant + row0 * RED_ROW);
            float2* dst = (float2*)red_sm;
            #pragma unroll
            for (int i = tid; i < ROWS * RED_ROW / 2; i += 256) dst[i] = src[i];
        }
        __syncthreads();

        // ---- per-row partials: 8 threads per row, no cross-lane ops ----
        {
            const float* tpr = tp_sm + r * TP_ROW;
            float pp = 1.0f;
            #pragma unroll
            for (int t = s; t < 34; t += 8) {
                const float* e = tpr + t * 7;
                float c0 = e[0], c1 = e[1], c2 = e[2], c3 = e[3];
                float c4 = e[4], c5 = e[5], c6 = e[6];
                // prob > 0 by construction; tile_hidden_ct in [0.5,1.5] -> no inf/nan
                float term = c0 * exp2f(c1 * log2f(prob_sm[t])) + c6 + (c3 * c2 / c4) * c5;
                pp *= term;
            }
            float ps = 0.0f;
            const float* fr = fan_sm + r * FAN_ROW;
            #pragma unroll
            for (int f = s; f < 80; f += 8) ps += fr[f] * fc_sm[f];
            pprod[s][r] = pp;
            psum[s][r] = ps;
        }
        __syncthreads();

        // ---- finalize final_prob_throw for the 32 rows ----
        if (tid < 32) {
            float p = 1.0f, q = 0.0f;
            #pragma unroll
            for (int s2 = 0; s2 < 8; ++s2) { p *= pprod[s2][tid]; q += psum[s2][tid]; }
            float fin = p * 100.0f * q;
            final_sm[tid] = fin;
            fsum_part += fin;   // for g==0 op-sum
        }
        __syncthreads();

        // ---- stage 3: tile_bound_winrate partials (lane = tile idx) ----
        if (lane < 34) {
            #pragma unroll
            for (int i = 0; i < 8; ++i) {
                int rr = wave * 8 + i;
                acc3 += red_sm[rr * RED_ROW + lane] * final_sm[rr];
            }
        }
    }

    if (lane < 34) acc_sm[wave][lane] = acc3;
    __syncthreads();

    // ---- outputs (wave 0 only) ----
    if (wave == 0) {
        float tbw = 0.0f;
        if (lane < 34)
            tbw = acc_sm[0][lane] + acc_sm[1][lane] + acc_sm[2][lane] + acc_sm[3][lane];
        if (g == 0) {
            if (lane < 34)
                out_weighted[(size_t)b * 34 + lane] = tbw * tile_coeff[lane];
            float fs = fsum_part;  // lanes 0..31 hold partials, 32..63 hold 0
            #pragma unroll
            for (int sh = 1; sh < 64; sh <<= 1) fs += __shfl_xor(fs, sh);
            if (lane == 0) out_max[(size_t)b * 5] = fs;
        } else {
            float m = (lane < 34) ? tbw : -INFINITY;
            #pragma unroll
            for (int sh = 1; sh < 64; sh <<= 1) m = fmaxf(m, __shfl_xor(m, sh));
            if (lane == 0) out_max[(size_t)b * 5 + g] = m;
        }
    }
}

extern "C" void kernel_launch(void* const* d_in, const int* in_sizes, int n_in,
                              void* d_out, int out_size, void* d_ws, size_t ws_size,
                              hipStream_t stream) {
    const float* meta       = (const float*)d_in[0];
    const float* wall       = (const float*)d_in[1];
    const float* tile_prep  = (const float*)d_in[2];
    const float* fan_prep   = (const float*)d_in[3];
    const float* redundant  = (const float*)d_in[4];
    // d_in[5] count_prep, d_in[6] chi_peng_count_remain: unused by reference
    const float* W_throw    = (const float*)d_in[7];
    const float* b_throw    = (const float*)d_in[8];
    const float* fan_coeff  = (const float*)d_in[9];
    const float* fan_mult   = (const float*)d_in[10];
    const float* tile_coeff = (const float*)d_in[11];

    int n = in_sizes[0] / 6;
    float* out_max      = (float*)d_out;            // (n,5)
    float* out_weighted = out_max + (size_t)n * 5;  // (n,34)

    dim3 grid(n * 5), block(256);
    hipLaunchKernelGGL(mahjong_kernel, grid, block, 0, stream,
                       meta, wall, tile_prep, fan_prep, redundant,
                       W_throw, b_throw, fan_coeff, fan_mult, tile_coeff,
                       out_max, out_weighted, n);
}

// Round 3
// 512.203 us; speedup vs baseline: 1.1664x; 1.1664x over previous
//
#include <hip/hip_runtime.h>
#include <math.h>

#define N_OPS 320

__global__ __launch_bounds__(256) void mahjong_kernel(
    const float* __restrict__ meta,        // (N,6)
    const float* __restrict__ wall,        // (N,34,5)
    const float* __restrict__ tile_prep,   // (N,320,34,7)
    const float* __restrict__ fan_prep,    // (N,320,80)
    const float* __restrict__ redundant,   // (N,320,34)
    const float* __restrict__ W_throw,     // (11)
    const float* __restrict__ b_throw,     // (1)
    const float* __restrict__ fan_coeff,   // (80)
    const float* __restrict__ fan_mult,    // (80)
    const float* __restrict__ tile_coeff,  // (34)
    float* __restrict__ out_max,           // (N,5)
    float* __restrict__ out_weighted,      // (N,34)
    int n)
{
    const int blk  = blockIdx.x;
    const int b    = blk / 5;
    const int g    = blk % 5;
    const int tid  = threadIdx.x;
    const int wave = tid >> 6;
    const int lane = tid & 63;

    // small LDS footprint -> occupancy not LDS-limited
    __shared__ float terms_sm[32 * 34];   // one float per (row, tile)
    __shared__ float qp_sm[32 * 21];      // fan quad-partials, padded stride 21
    __shared__ float prob_sm[34];
    __shared__ float fc_sm[80];
    __shared__ float final_sm[32];
    __shared__ float acc_sm[4][34];

    // ---- stage 0: prob_throw (Linear(11,1)) and fused fan coeff ----
    if (tid < 34) {
        float acc = b_throw[0];
        #pragma unroll
        for (int j = 0; j < 6; ++j) acc += meta[(size_t)b * 6 + j] * W_throw[j];
        const float* w = wall + ((size_t)b * 34 + tid) * 5;
        #pragma unroll
        for (int j = 0; j < 5; ++j) acc += w[j] * W_throw[6 + j];
        prob_sm[tid] = acc;
    }
    if (tid >= 64 && tid < 144) {
        int f = tid - 64;
        fc_sm[f] = fan_coeff[f] * fan_mult[f];
    }
    __syncthreads();

    float acc3 = 0.0f;       // stage-3 per-wave accumulator (lane < 34)
    float fsum_part = 0.0f;  // g==0: threads 0..31 accumulate final sums

    const int t_init = tid % 34;  // tile index of tau = tid

    for (int c = 0; c < 2; ++c) {
        const size_t row0 = (size_t)b * N_OPS + g * 64 + c * 32;

        if (c) __syncthreads();  // protect LDS reuse across chunks

        // ---- tile terms: direct global load of 7 floats per tile, reduce to 1 ----
        // flat tile id tau in [0,1088): float offset within chunk = 7*tau
        {
            const float* tp0 = tile_prep + row0 * 238;
            int t = t_init;
            #pragma unroll
            for (int k = 0; k < 4; ++k) {
                const int tau = tid + 256 * k;
                const float* e = tp0 + 7 * tau;
                float c0 = e[0], c1 = e[1], c2 = e[2], c3 = e[3];
                float c4 = e[4], c5 = e[5], c6 = e[6];
                // prob>0 by construction; tile_hidden_ct in [0.5,1.5] -> no inf/nan
                float term = c0 * exp2f(c1 * log2f(prob_sm[t])) + c6 + (c3 * c2 / c4) * c5;
                terms_sm[tau] = term;
                t += 18; if (t >= 34) t -= 34;   // (tau+256) % 34
            }
            if (tid < 64) {  // tail: tiles 1024..1087
                const int tau = 1024 + tid;
                int t2 = tid + 4;                 // 1024 % 34 == 4
                if (t2 >= 34) t2 -= 34;
                if (t2 >= 34) t2 -= 34;
                const float* e = tp0 + 7 * tau;
                float c0 = e[0], c1 = e[1], c2 = e[2], c3 = e[3];
                float c4 = e[4], c5 = e[5], c6 = e[6];
                float term = c0 * exp2f(c1 * log2f(prob_sm[t2])) + c6 + (c3 * c2 / c4) * c5;
                terms_sm[tau] = term;
            }
        }

        // ---- fan quad-partials: coalesced float4, reduce 4 -> 1 immediately ----
        {
            const float4* fsrc = (const float4*)(fan_prep + row0 * 80);
            #pragma unroll
            for (int k = 0; k < 3; ++k) {
                const int i = tid + 256 * k;
                if (i < 640) {
                    float4 v = fsrc[i];
                    const int r = i / 20;
                    const int q = i - r * 20;
                    const int f = 4 * q;
                    qp_sm[r * 21 + q] = v.x * fc_sm[f]     + v.y * fc_sm[f + 1]
                                      + v.z * fc_sm[f + 2] + v.w * fc_sm[f + 3];
                }
            }
        }
        __syncthreads();

        // ---- finalize final_prob_throw per row (threads 0..31) ----
        if (tid < 32) {
            const float* tr = terms_sm + tid * 34;
            float p = 1.0f;
            #pragma unroll
            for (int t = 0; t < 34; ++t) p *= tr[t];
            const float* qr = qp_sm + tid * 21;
            float q = 0.0f;
            #pragma unroll
            for (int j = 0; j < 20; ++j) q += qr[j];
            float fin = p * 100.0f * q;
            final_sm[tid] = fin;
            fsum_part += fin;
        }
        __syncthreads();

        // ---- stage 3: tile_bound_winrate partials, direct global redundant ----
        if (lane < 34) {
            const float* rr0 = redundant + (row0 + wave * 8) * 34;
            #pragma unroll
            for (int i = 0; i < 8; ++i)
                acc3 += rr0[i * 34 + lane] * final_sm[wave * 8 + i];
        }
    }

    if (lane < 34) acc_sm[wave][lane] = acc3;
    __syncthreads();

    // ---- outputs (wave 0 only) ----
    if (wave == 0) {
        float tbw = 0.0f;
        if (lane < 34)
            tbw = acc_sm[0][lane] + acc_sm[1][lane] + acc_sm[2][lane] + acc_sm[3][lane];
        if (g == 0) {
            if (lane < 34)
                out_weighted[(size_t)b * 34 + lane] = tbw * tile_coeff[lane];
            float fs = fsum_part;  // lanes 0..31 hold partials; 32..63 hold 0
            #pragma unroll
            for (int sh = 1; sh < 64; sh <<= 1) fs += __shfl_xor(fs, sh);
            if (lane == 0) out_max[(size_t)b * 5] = fs;
        } else {
            float m = (lane < 34) ? tbw : -INFINITY;
            #pragma unroll
            for (int sh = 1; sh < 64; sh <<= 1) m = fmaxf(m, __shfl_xor(m, sh));
            if (lane == 0) out_max[(size_t)b * 5 + g] = m;
        }
    }
}

extern "C" void kernel_launch(void* const* d_in, const int* in_sizes, int n_in,
                              void* d_out, int out_size, void* d_ws, size_t ws_size,
                              hipStream_t stream) {
    const float* meta       = (const float*)d_in[0];
    const float* wall       = (const float*)d_in[1];
    const float* tile_prep  = (const float*)d_in[2];
    const float* fan_prep   = (const float*)d_in[3];
    const float* redundant  = (const float*)d_in[4];
    // d_in[5] count_prep, d_in[6] chi_peng_count_remain: unused by reference
    const float* W_throw    = (const float*)d_in[7];
    const float* b_throw    = (const float*)d_in[8];
    const float* fan_coeff  = (const float*)d_in[9];
    const float* fan_mult   = (const float*)d_in[10];
    const float* tile_coeff = (const float*)d_in[11];

    int n = in_sizes[0] / 6;
    float* out_max      = (float*)d_out;            // (n,5)
    float* out_weighted = out_max + (size_t)n * 5;  // (n,34)

    dim3 grid(n * 5), block(256);
    hipLaunchKernelGGL(mahjong_kernel, grid, block, 0, stream,
                       meta, wall, tile_prep, fan_prep, redundant,
                       W_throw, b_throw, fan_coeff, fan_mult, tile_coeff,
                       out_max, out_weighted, n);
}